// Round 13
// baseline (19417.104 us; speedup 1.0000x reference)
//
#include <hip/hip_runtime.h>
#include <math.h>

// ---------------------------------------------------------------------------
// R13 = R12 with the asm-constraint compile fix (ext_vector_type operands for
// vector asm ins/outs; HIP float4 is a struct and rejects 'v' inputs).
// Design unchanged from R12 (see prediction there):
//  1. h export: [slot][unit][batch] ring + contiguous-batch mapping -> ONE
//     global_store_dwordx4 sc0 sc1 per thread (full-line writes, no RMW amp).
//  2. ONE merged pollwait per beat (lanes 0-7 upstream>=t+1, 8-15
//     downstream>=t-3, 16-23 peers>=t).
//  3. both staging load sets before a single vmcnt(0).
//  4. L2/L3 ih weights LDS-resident; L4 ih L2-streamed.
// Skeleton (proven 18.2ms): LLC transport sc0sc1 loads + agent-atomic flags,
// ring depth 4, bounded-spin diagnostic, hh weights in LDS, 1 block/CU.
// ---------------------------------------------------------------------------

typedef float vf4 __attribute__((ext_vector_type(4)));
typedef float vf2 __attribute__((ext_vector_type(2)));

__device__ __forceinline__ float sigmoidf_(float v) {
    return 1.0f / (1.0f + __expf(-v));
}

// src[(g*H+u)*J + j] -> dst[(u*3+g)*J + j]
__global__ void prep_k(const float* __restrict__ src, float* __restrict__ dst,
                       int H, int J) {
    int idx = blockIdx.x * 256 + threadIdx.x;
    int total = 3 * H * J;
    if (idx < total) {
        int g = idx / (H * J);
        int rem = idx - g * H * J;
        int u = rem / J;
        int j = rem - u * J;
        dst[(u * 3 + g) * J + j] = src[(g * H + u) * J + j];
    }
}

// ---- transport primitives --------------------------------------------------

__device__ __forceinline__ void flag_st(int* p, int v) {
    __hip_atomic_store(p, v, __ATOMIC_RELAXED, __HIP_MEMORY_SCOPE_AGENT);
}
__device__ __forceinline__ int flag_ld(const int* p) {
    return __hip_atomic_load(p, __ATOMIC_RELAXED, __HIP_MEMORY_SCOPE_AGENT);
}

// ONE merged wait per beat; bounded spin -> absmax diagnostic, not a hang.
__device__ __forceinline__ void pollwait(const int* p, int tgt, bool active) {
    if (threadIdx.x < 64) {
        int spins = 0;
        while (true) {
            int v = active ? flag_ld(p) : 0x7fffffff;
            if (__all(v >= tgt)) break;
            if (++spins > 200000) break;
            __builtin_amdgcn_s_sleep(1);
        }
    }
    __syncthreads();
}

// ---- staging: ring is [slot][u(J)][b(32)]; LDS dest is [b][J+4] -----------
template <int J>
__device__ __forceinline__ void ld_chunks(vf4* t, const float* src) {
    constexpr int N = (32 * J) / 1024;
    #pragma unroll
    for (int k = 0; k < N; ++k) {
        const float* p = src + (size_t)(k * 256 + threadIdx.x) * 4;
        asm volatile("global_load_dwordx4 %0, %1, off sc0 sc1"
                     : "=v"(t[k]) : "v"(p) : "memory");
    }
}
template <int J>
__device__ __forceinline__ void wr_chunks(float* dst, const vf4* t) {
    constexpr int N = (32 * J) / 1024;
    #pragma unroll
    for (int k = 0; k < N; ++k) {
        int i = (k * 256 + threadIdx.x) * 4;
        int u = i >> 5;
        int b4 = i & 31;
        dst[(b4 + 0) * (J + 4) + u] = t[k].x;
        dst[(b4 + 1) * (J + 4) + u] = t[k].y;
        dst[(b4 + 2) * (J + 4) + u] = t[k].z;
        dst[(b4 + 3) * (J + 4) + u] = t[k].w;
    }
}
template <int J1, int J2>
__device__ __forceinline__ void stagePair(float* d1, const float* s1,
                                          float* d2, const float* s2) {
    vf4 t1[(32 * J1) / 1024];
    vf4 t2[(32 * J2) / 1024];
    ld_chunks<J1>(t1, s1);
    ld_chunks<J2>(t2, s2);
    asm volatile("s_waitcnt vmcnt(0)" ::: "memory");
    wr_chunks<J1>(d1, t1);
    wr_chunks<J2>(d2, t2);
}
template <int J>
__device__ __forceinline__ void stageOne(float* d, const float* s) {
    vf4 t[(32 * J) / 1024];
    ld_chunks<J>(t, s);
    asm volatile("s_waitcnt vmcnt(0)" ::: "memory");
    wr_chunks<J>(d, t);
}

template <int J>
__device__ __forceinline__ void zero32(float* dst) {
    for (int i = threadIdx.x; i < 32 * (J + 4); i += 256) dst[i] = 0.0f;
}

// acc{r,z,c} += w{R,Z,N} . h[row] for KB CONTIGUOUS batch rows b00..b00+KB-1
template <int KB, int J>
__device__ __forceinline__ void dot3(const float* __restrict__ w3,
                                     const float* __restrict__ hst, int b00,
                                     float* ar, float* az, float* ac) {
    const float4* wr = (const float4*)w3;
    const float4* wz = (const float4*)(w3 + J);
    const float4* wn = (const float4*)(w3 + 2 * J);
    const float* rows[KB];
    #pragma unroll
    for (int k = 0; k < KB; ++k) rows[k] = hst + (b00 + k) * (J + 4);
    #pragma unroll 4
    for (int j4 = 0; j4 < J / 4; ++j4) {
        float4 a = wr[j4];
        float4 c = wz[j4];
        float4 d = wn[j4];
        #pragma unroll
        for (int k = 0; k < KB; ++k) {
            float4 hv = *(const float4*)(rows[k] + j4 * 4);
            ar[k] = fmaf(hv.x, a.x, ar[k]); ar[k] = fmaf(hv.y, a.y, ar[k]);
            ar[k] = fmaf(hv.z, a.z, ar[k]); ar[k] = fmaf(hv.w, a.w, ar[k]);
            az[k] = fmaf(hv.x, c.x, az[k]); az[k] = fmaf(hv.y, c.y, az[k]);
            az[k] = fmaf(hv.z, c.z, az[k]); az[k] = fmaf(hv.w, c.w, az[k]);
            ac[k] = fmaf(hv.x, d.x, ac[k]); ac[k] = fmaf(hv.y, d.y, ac[k]);
            ac[k] = fmaf(hv.z, d.z, ac[k]); ac[k] = fmaf(hv.w, d.w, ac[k]);
        }
    }
}

__device__ __forceinline__ void st_x4(float* p, vf4 v) {
    asm volatile("global_store_dwordx4 %0, %1, off sc0 sc1"
                 :: "v"(p), "v"(v) : "memory");
}
__device__ __forceinline__ void st_x2(float* p, vf2 v) {
    asm volatile("global_store_dwordx2 %0, %1, off sc0 sc1"
                 :: "v"(p), "v"(v) : "memory");
}

__global__ __launch_bounds__(256) void gru_pipe_kernel(
    const float* __restrict__ x,
    const float* __restrict__ w_ih1,
    const float* __restrict__ b_ih1, const float* __restrict__ b_hh1,
    const float* __restrict__ b_ih2, const float* __restrict__ b_hh2,
    const float* __restrict__ b_ih3, const float* __restrict__ b_hh3,
    const float* __restrict__ b_ih4, const float* __restrict__ b_hh4,
    const float* __restrict__ wA_hh1,  // [256][3][256]
    const float* __restrict__ wA_ih2,  // [128][3][256]
    const float* __restrict__ wA_hh2,  // [128][3][128]
    const float* __restrict__ wA_ih3,  // [128][3][128]
    const float* __restrict__ wA_hh3,  // [128][3][128]
    const float* __restrict__ wA_ih4,  // [256][3][128]
    const float* __restrict__ wA_hh4,  // [256][3][256]
    const float* __restrict__ w_out, const float* __restrict__ b_out,
    int* __restrict__ flags,  // [8 bg][4 stages x 32 ints (128B line)]
    float* __restrict__ ex,   // [8 bg][98304] h rings, [slot][u][b] layout
    float* __restrict__ out)  // [256][1024] pre-zeroed
{
    const int tid = threadIdx.x;
    extern __shared__ float smem[];
    __shared__ float xs[32];
    __shared__ float wsum[4][4][8];

    const int bg = blockIdx.x & 7;
    const int rest = blockIdx.x >> 3;
    const int s = rest >> 3;              // stage 0..3
    const int us = rest & 7;              // unit slice 0..7

    int* fb = flags + bg * 128;
    int* arr_own = fb + s * 32;

    // merged per-lane poll assignment (wave0)
    const int* pp = arr_own; int dd = -1000000000; bool act = false;
    if (tid < 8) {
        if (s > 0) { pp = fb + (s - 1) * 32 + tid; dd = 1; act = true; }
    } else if (tid < 16) {
        if (s < 3) { pp = fb + (s + 1) * 32 + (tid - 8); dd = -3; act = true; }
    } else if (tid < 24) {
        pp = fb + s * 32 + (tid - 16); dd = 0; act = true;
    }

    float* exb = ex + (size_t)bg * 98304;
    float* h1r = exb;            // 4 slots x [256u][32b]
    float* h2r = exb + 32768;    // 4 x [128u][32b]
    float* h3r = exb + 49152;
    float* h4r = exb + 65536;

    if (s == 0) {
        // ---- layer 1: in=1 scalar, H=256, 32 units/slice, KB=4 ----
        float* wlds = smem;            // [32][772]
        float* hprev = smem + 24704;   // [32][260]
        {
            const float* srcw = wA_hh1 + (size_t)us * 32 * 768;
            for (int i = tid; i < 24576; i += 256) {
                int uu = i / 768, r = i - uu * 768;
                wlds[uu * 772 + r] = srcw[i];
            }
        }
        __syncthreads();
        const int ul = tid >> 3, b0 = tid & 7;
        const int b00 = b0 * 4;
        const int u = us * 32 + ul;
        const float* wh = wlds + ul * 772;
        const float br = b_ih1[u] + b_hh1[u];
        const float bz = b_ih1[u + 256] + b_hh1[u + 256];
        const float bxn = b_ih1[u + 512];
        const float bhn = b_hh1[u + 512];
        const float wir = w_ih1[u], wiz = w_ih1[u + 256], win = w_ih1[u + 512];
        for (int t = 0; t < 1024; ++t) {
            pollwait(pp, t + dd, act);
            if (tid < 32) xs[tid] = x[(size_t)(bg * 32 + tid) * 1024 + t];
            if (t > 0) stageOne<256>(hprev, h1r + (size_t)((t - 1) & 3) * 8192);
            else       zero32<256>(hprev);
            __syncthreads();
            float ar[4], az[4], axn[4], ahn[4];
            #pragma unroll
            for (int k = 0; k < 4; ++k) {
                float xv = xs[b00 + k];
                ar[k] = br + xv * wir; az[k] = bz + xv * wiz;
                axn[k] = bxn + xv * win; ahn[k] = bhn;
            }
            dot3<4, 256>(wh, hprev, b00, ar, az, ahn);
            vf4 ho;
            #pragma unroll
            for (int k = 0; k < 4; ++k) {
                float hp = hprev[(b00 + k) * 260 + u];
                float r = sigmoidf_(ar[k]);
                float z = sigmoidf_(az[k]);
                float n = tanhf(axn[k] + r * ahn[k]);
                ho[k] = (1.f - z) * n + z * hp;
            }
            st_x4(h1r + (size_t)(t & 3) * 8192 + (size_t)u * 32 + b00, ho);
            asm volatile("s_waitcnt vmcnt(0)" ::: "memory");
            __syncthreads();
            if (tid == 0) flag_st(arr_own + us, t + 1);
        }
    } else if (s == 1) {
        // ---- layer 2: in=256, H=128, 16 units/slice, KB=2, ih in LDS ----
        float* whh = smem;             // [16][388]
        float* wih = smem + 6208;      // [16][772]
        float* hin = smem + 18560;     // [32][260]
        float* hprev = smem + 26880;   // [32][132]
        {
            const float* srcw = wA_hh2 + (size_t)us * 16 * 384;
            for (int i = tid; i < 6144; i += 256) {
                int uu = i / 384, r = i - uu * 384;
                whh[uu * 388 + r] = srcw[i];
            }
            const float* srci = wA_ih2 + (size_t)us * 16 * 768;
            for (int i = tid; i < 12288; i += 256) {
                int uu = i / 768, r = i - uu * 768;
                wih[uu * 772 + r] = srci[i];
            }
        }
        __syncthreads();
        const int ul = tid >> 4, b0 = tid & 15;
        const int b00 = b0 * 2;
        const int u = us * 16 + ul;
        const float* wi = wih + ul * 772;
        const float* wh = whh + ul * 388;
        const float br = b_ih2[u] + b_hh2[u];
        const float bz = b_ih2[u + 128] + b_hh2[u + 128];
        const float bxn = b_ih2[u + 256];
        const float bhn = b_hh2[u + 256];
        for (int t = 0; t < 1024; ++t) {
            pollwait(pp, t + dd, act);
            if (t > 0) {
                stagePair<256, 128>(hin, h1r + (size_t)(t & 3) * 8192,
                                    hprev, h2r + (size_t)((t - 1) & 3) * 4096);
            } else {
                stageOne<256>(hin, h1r);
                zero32<128>(hprev);
            }
            __syncthreads();
            float ar[2] = {br, br}, az[2] = {bz, bz};
            float axn[2] = {bxn, bxn}, ahn[2] = {bhn, bhn};
            dot3<2, 256>(wi, hin, b00, ar, az, axn);
            dot3<2, 128>(wh, hprev, b00, ar, az, ahn);
            vf2 ho;
            #pragma unroll
            for (int k = 0; k < 2; ++k) {
                float hp = hprev[(b00 + k) * 132 + u];
                float r = sigmoidf_(ar[k]);
                float z = sigmoidf_(az[k]);
                float n = tanhf(axn[k] + r * ahn[k]);
                ho[k] = (1.f - z) * n + z * hp;
            }
            st_x2(h2r + (size_t)(t & 3) * 4096 + (size_t)u * 32 + b00, ho);
            asm volatile("s_waitcnt vmcnt(0)" ::: "memory");
            __syncthreads();
            if (tid == 0) flag_st(arr_own + us, t + 1);
        }
    } else if (s == 2) {
        // ---- layer 3: in=128, H=128, 16 units/slice, KB=2, ih in LDS ----
        float* whh = smem;             // [16][388]
        float* wih = smem + 6208;      // [16][388]
        float* hin = smem + 12416;     // [32][132]
        float* hprev = smem + 16640;   // [32][132]
        {
            const float* srcw = wA_hh3 + (size_t)us * 16 * 384;
            for (int i = tid; i < 6144; i += 256) {
                int uu = i / 384, r = i - uu * 384;
                whh[uu * 388 + r] = srcw[i];
            }
            const float* srci = wA_ih3 + (size_t)us * 16 * 384;
            for (int i = tid; i < 6144; i += 256) {
                int uu = i / 384, r = i - uu * 384;
                wih[uu * 388 + r] = srci[i];
            }
        }
        __syncthreads();
        const int ul = tid >> 4, b0 = tid & 15;
        const int b00 = b0 * 2;
        const int u = us * 16 + ul;
        const float* wi = wih + ul * 388;
        const float* wh = whh + ul * 388;
        const float br = b_ih3[u] + b_hh3[u];
        const float bz = b_ih3[u + 128] + b_hh3[u + 128];
        const float bxn = b_ih3[u + 256];
        const float bhn = b_hh3[u + 256];
        for (int t = 0; t < 1024; ++t) {
            pollwait(pp, t + dd, act);
            if (t > 0) {
                stagePair<128, 128>(hin, h2r + (size_t)(t & 3) * 4096,
                                    hprev, h3r + (size_t)((t - 1) & 3) * 4096);
            } else {
                stageOne<128>(hin, h2r);
                zero32<128>(hprev);
            }
            __syncthreads();
            float ar[2] = {br, br}, az[2] = {bz, bz};
            float axn[2] = {bxn, bxn}, ahn[2] = {bhn, bhn};
            dot3<2, 128>(wi, hin, b00, ar, az, axn);
            dot3<2, 128>(wh, hprev, b00, ar, az, ahn);
            vf2 ho;
            #pragma unroll
            for (int k = 0; k < 2; ++k) {
                float hp = hprev[(b00 + k) * 132 + u];
                float r = sigmoidf_(ar[k]);
                float z = sigmoidf_(az[k]);
                float n = tanhf(axn[k] + r * ahn[k]);
                ho[k] = (1.f - z) * n + z * hp;
            }
            st_x2(h3r + (size_t)(t & 3) * 4096 + (size_t)u * 32 + b00, ho);
            asm volatile("s_waitcnt vmcnt(0)" ::: "memory");
            __syncthreads();
            if (tid == 0) flag_st(arr_own + us, t + 1);
        }
    } else {
        // ---- layer 4: in=128, H=256, 32 units/slice, KB=4, + projection ----
        float* wlds = smem;            // [32][772] hh
        float* hin = smem + 24704;     // [32][132]
        float* hprev = smem + 28928;   // [32][260]
        {
            const float* srcw = wA_hh4 + (size_t)us * 32 * 768;
            for (int i = tid; i < 24576; i += 256) {
                int uu = i / 768, r = i - uu * 768;
                wlds[uu * 772 + r] = srcw[i];
            }
        }
        __syncthreads();
        const int ul = tid >> 3, b0 = tid & 7;
        const int b00 = b0 * 4;
        const int u = us * 32 + ul;
        const float* wi = wA_ih4 + (size_t)u * 384;   // L2-streamed
        const float* wh = wlds + ul * 772;
        const float br = b_ih4[u] + b_hh4[u];
        const float bz = b_ih4[u + 256] + b_hh4[u + 256];
        const float bxn = b_ih4[u + 512];
        const float bhn = b_hh4[u + 512];
        const float wo = w_out[u];
        for (int t = 0; t < 1024; ++t) {
            pollwait(pp, t + dd, act);
            if (t > 0) {
                stagePair<128, 256>(hin, h3r + (size_t)(t & 3) * 4096,
                                    hprev, h4r + (size_t)((t - 1) & 3) * 8192);
            } else {
                stageOne<128>(hin, h3r);
                zero32<256>(hprev);
            }
            __syncthreads();
            float ar[4], az[4], axn[4], ahn[4];
            #pragma unroll
            for (int k = 0; k < 4; ++k) {
                ar[k] = br; az[k] = bz; axn[k] = bxn; ahn[k] = bhn;
            }
            dot3<4, 128>(wi, hin, b00, ar, az, axn);
            dot3<4, 256>(wh, hprev, b00, ar, az, ahn);
            vf4 ho;
            float pk[4];
            #pragma unroll
            for (int k = 0; k < 4; ++k) {
                float hp = hprev[(b00 + k) * 260 + u];
                float r = sigmoidf_(ar[k]);
                float z = sigmoidf_(az[k]);
                float n = tanhf(axn[k] + r * ahn[k]);
                float hnew = (1.f - z) * n + z * hp;
                ho[k] = hnew;
                pk[k] = wo * hnew;
            }
            st_x4(h4r + (size_t)(t & 3) * 8192 + (size_t)u * 32 + b00, ho);
            // reduce over the wave's 8 unit-lanes (lane bits 3..5)
            #pragma unroll
            for (int k = 0; k < 4; ++k) {
                pk[k] += __shfl_xor(pk[k], 8, 64);
                pk[k] += __shfl_xor(pk[k], 16, 64);
                pk[k] += __shfl_xor(pk[k], 32, 64);
            }
            if ((tid & 63) < 8) {
                int w = tid >> 6;
                #pragma unroll
                for (int k = 0; k < 4; ++k) wsum[w][k][tid & 7] = pk[k];
            }
            asm volatile("s_waitcnt vmcnt(0)" ::: "memory");
            __syncthreads();
            if (tid == 0) flag_st(arr_own + us, t + 1);
            if (tid < 32) {
                int k = tid >> 3, bb = tid & 7;
                float ssum = wsum[0][k][bb] + wsum[1][k][bb] +
                             wsum[2][k][bb] + wsum[3][k][bb];
                if (us == 0) ssum += b_out[0];
                atomicAdd(out + (size_t)(bg * 32 + bb * 4 + k) * 1024 + t, ssum);
            }
        }
    }
}

extern "C" void kernel_launch(void* const* d_in, const int* in_sizes, int n_in,
                              void* d_out, int out_size, void* d_ws, size_t ws_size,
                              hipStream_t stream) {
    const float* x     = (const float*)d_in[0];
    const float* w_ih1 = (const float*)d_in[1];
    const float* w_hh1 = (const float*)d_in[2];
    const float* b_ih1 = (const float*)d_in[3];
    const float* b_hh1 = (const float*)d_in[4];
    const float* w_ih2 = (const float*)d_in[5];
    const float* w_hh2 = (const float*)d_in[6];
    const float* b_ih2 = (const float*)d_in[7];
    const float* b_hh2 = (const float*)d_in[8];
    const float* w_ih3 = (const float*)d_in[9];
    const float* w_hh3 = (const float*)d_in[10];
    const float* b_ih3 = (const float*)d_in[11];
    const float* b_hh3 = (const float*)d_in[12];
    const float* w_ih4 = (const float*)d_in[13];
    const float* w_hh4 = (const float*)d_in[14];
    const float* b_ih4 = (const float*)d_in[15];
    const float* b_hh4 = (const float*)d_in[16];
    const float* w_out = (const float*)d_in[17];
    const float* b_out = (const float*)d_in[18];

    float* ws = (float*)d_ws;
    float* wA_hh1 = ws;                  // 196608
    float* wA_ih2 = wA_hh1 + 196608;     //  98304
    float* wA_hh2 = wA_ih2 + 98304;      //  49152
    float* wA_ih3 = wA_hh2 + 49152;      //  49152
    float* wA_hh3 = wA_ih3 + 49152;      //  49152
    float* wA_ih4 = wA_hh3 + 49152;      //  98304
    float* wA_hh4 = wA_ih4 + 98304;      // 196608
    float* ex     = wA_hh4 + 196608;     // 786432 (8 bg x 98304)
    int*   flags  = (int*)(ex + 786432); // 8 x 128 ints

    (void)hipMemsetAsync(flags, 0, 1024 * sizeof(int), stream);
    (void)hipMemsetAsync(d_out, 0, 256 * 1024 * sizeof(float), stream);

    prep_k<<<768, 256, 0, stream>>>(w_hh1, wA_hh1, 256, 256);
    prep_k<<<384, 256, 0, stream>>>(w_ih2, wA_ih2, 128, 256);
    prep_k<<<192, 256, 0, stream>>>(w_hh2, wA_hh2, 128, 128);
    prep_k<<<192, 256, 0, stream>>>(w_ih3, wA_ih3, 128, 128);
    prep_k<<<192, 256, 0, stream>>>(w_hh3, wA_hh3, 128, 128);
    prep_k<<<384, 256, 0, stream>>>(w_ih4, wA_ih4, 256, 128);
    prep_k<<<768, 256, 0, stream>>>(w_hh4, wA_hh4, 256, 256);

    // 149KB dynamic LDS (max over stages; L4 = 37248 floats): 1 block/CU.
    const int dyn_lds = 37248 * (int)sizeof(float);
    (void)hipFuncSetAttribute((const void*)gru_pipe_kernel,
                              hipFuncAttributeMaxDynamicSharedMemorySize, dyn_lds);

    gru_pipe_kernel<<<256, 256, dyn_lds, stream>>>(
        x, w_ih1, b_ih1, b_hh1, b_ih2, b_hh2, b_ih3, b_hh3, b_ih4, b_hh4,
        wA_hh1, wA_ih2, wA_hh2, wA_ih3, wA_hh3, wA_ih4, wA_hh4,
        w_out, b_out, flags, ex, (float*)d_out);
}